// Round 16
// baseline (414.750 us; speedup 1.0000x reference)
//
#include <hip/hip_runtime.h>
#include <stdint.h>

// Depthwise causal conv, split into:
//  (1) zero_upper: streams the strictly-upper triangle (zeros) as contiguous
//      row tails at write bandwidth.
//  (2) dwconv_tiles: PERSISTENT 2048 blocks (8/CU) loop over the 16896
//      lower-triangle 64x64 tiles (static stride) -- no per-tile dispatch
//      cost, resident blocks destagger so stage latency hides under other
//      blocks' compute. Body = R14 proven-clean one-shot MFMA Toeplitz:
//      A[m=q,k]=w[r,k-m-3], B[k,n=p]=x_tile -> float4 stores, 0 conflicts.
// N=2, C=16, H=W=2048.

#define HDIM 2048
#define WDIM 2048
#define CH   16
#define NPLANE 32
#define PITCH 80             // f16 per LDS row (160B): measured 0 conflicts (r14)
#define XROWS 69             // 64 + 5 halo rows
#define NSL   (XROWS * 20)   // 16B staging granules: 1380
#define NTILES 528           // lower-tri tiles per plane (32*33/2)
#define TOTTILES (NPLANE * NTILES)  // 16896
#define NBLK 2048

typedef float    f32x4 __attribute__((ext_vector_type(4)));
typedef __fp16   h16x2 __attribute__((ext_vector_type(2)));
typedef _Float16 f16x8 __attribute__((ext_vector_type(8)));

// ---------------- kernel 1: upper-triangle zeros (row tails) ----------------
__global__ __launch_bounds__(256, 8)
void zero_upper(float* __restrict__ out) {
  const int gw = ((blockIdx.x << 8) + threadIdx.x) >> 6;  // 4096 waves
  const int lane = threadIdx.x & 63;
  const float4 z = make_float4(0.f, 0.f, 0.f, 0.f);
  for (int r = gw; r < NPLANE * HDIM; r += 4096) {  // r = plane*2048 + p
    const int p = r & (HDIM - 1);
    float* row = out + ((size_t)r << 11);
    int c0 = p + 1;
    if (c0 >= WDIM) continue;
    int a0 = (c0 + 3) & ~3;
    int head = a0 - c0;
    if (head > WDIM - c0) head = WDIM - c0;
    if (lane < head) row[c0 + lane] = 0.f;
    for (int c = a0 + 4 * lane; c < WDIM; c += 256)
      *(float4*)(row + c) = z;
  }
}

// ---------------- kernel 2: persistent lower-triangle compute ----------------
__global__ __launch_bounds__(256, 8)
void dwconv_tiles(const float* __restrict__ x, const float* __restrict__ wgt,
                  float* __restrict__ out) {
  __shared__ __attribute__((aligned(16))) _Float16 sx[XROWS * PITCH];  // 11 KB
  const int tid = threadIdx.x;
  const int lane = tid & 63;
  const int j16 = lane & 15;   // A: m / B: n / D: col
  const int wk  = lane >> 4;   // k-octet / D row quartet
  const int wid = tid >> 6;    // wave -> 16-row p-strip

#pragma unroll 1
  for (int f = blockIdx.x; f < TOTTILES; f += NBLK) {
    const int plane = f / NTILES;
    const int k = f - plane * NTILES;
    int by = (int)((sqrtf(8.f * k + 1.f) - 1.f) * 0.5f);
    while ((by + 1) * (by + 2) / 2 <= k) ++by;
    while (by * (by + 1) / 2 > k) --by;
    const int bx = k - by * (by + 1) / 2;     // 0 <= bx <= by <= 31
    const int p0 = by << 6, q0 = bx << 6;
    const size_t pb = (size_t)plane * ((size_t)HDIM * WDIM);
    const float* __restrict__ xp = x + pb;
    float* __restrict__ op = out + pb;

    // ---- Toeplitz A-fragments: lane holds A[m=j16, k=8wk+i] = w[r,k-m-3] ----
    const float* __restrict__ wcp = wgt + (plane & (CH - 1)) * 66;
    f16x8 aw[6];
#pragma unroll
    for (int r = 0; r < 6; ++r) {
#pragma unroll
      for (int i = 0; i < 8; ++i) {
        int d = 8 * wk + i - j16 - 3;  // tap index s
        aw[r][i] = (_Float16)((d >= 0 && d <= 10) ? wcp[r * 11 + d] : 0.f);
      }
    }

    // ---- Stage x tile as f16: rows [p0-5,p0+63], cols [q0-8,q0+72) ----
    const bool pure = (bx >= 1) && (by >= bx + 2);  // in-bounds AND causal
#pragma unroll
    for (int j = 0; j < 6; ++j) {
      int slot = j * 256 + tid;
      if (slot < NSL) {
        int row = slot / 20;
        int c4 = slot - row * 20;
        int ih = p0 - 5 + row;
        int cb = q0 - 8 + 4 * c4;
        float4 v = make_float4(0.f, 0.f, 0.f, 0.f);
        if (pure) {
          v = *(const float4*)(xp + (size_t)ih * WDIM + cb);
        } else if (ih >= 0) {  // ih <= p0+63 <= 2047 always
          bool fullv = (cb >= 0) && (cb + 3 <= ih) && (cb + 3 < WDIM);
          if (fullv) {
            v = *(const float4*)(xp + (size_t)ih * WDIM + cb);
          } else {
            float* vv = &v.x;
#pragma unroll
            for (int e = 0; e < 4; ++e) {
              int iw = cb + e;
              if (iw >= 0 && iw < WDIM && iw <= ih)
                vv[e] = xp[(size_t)ih * WDIM + iw];
            }
          }
        }
        union { h16x2 h[2]; uint2 u; } cv;
        cv.h[0] = __builtin_amdgcn_cvt_pkrtz(v.x, v.y);
        cv.h[1] = __builtin_amdgcn_cvt_pkrtz(v.z, v.w);
        *(uint2*)&sx[row * PITCH + 4 * c4] = cv.u;
      }
    }

    __syncthreads();

    // ---- Compute: 4 qt x 6 r = 24 MFMA per wave ----
    f32x4 acc[4];
#pragma unroll
    for (int qt = 0; qt < 4; ++qt) acc[qt] = (f32x4){0.f, 0.f, 0.f, 0.f};
#pragma unroll
    for (int qt = 0; qt < 4; ++qt) {
#pragma unroll
      for (int r = 0; r < 6; ++r) {
        // B[k=8wk+i, n=j16] = x_tile[16*wid + j16 + r, 16qt + 8wk + i]
        int off = (16 * wid + j16 + r) * PITCH + 16 * qt + 8 * wk;
        f16x8 xb = *(const f16x8*)&sx[off];
        acc[qt] =
            __builtin_amdgcn_mfma_f32_16x16x32_f16(aw[r], xb, acc[qt], 0, 0, 0);
      }
    }

    // ---- Store: D col = n = j16 (p-axis), row = m = 4wk+reg (q-axis) ----
    const int p = p0 + 16 * wid + j16;
    const bool dmask = (by == bx);  // only diagonal tiles cross p==q
#pragma unroll
    for (int qt = 0; qt < 4; ++qt) {
      const int q = q0 + 16 * qt + 4 * wk;
      f32x4 a = acc[qt];
      if (dmask) {
#pragma unroll
        for (int reg = 0; reg < 4; ++reg)
          if (q + reg > p) a[reg] = 0.f;
      }
      *(float4*)(op + (size_t)p * WDIM + q) =
          make_float4(a[0], a[1], a[2], a[3]);
    }

    __syncthreads();  // protect LDS before next iteration's stage
  }
}

extern "C" void kernel_launch(void* const* d_in, const int* in_sizes, int n_in,
                              void* d_out, int out_size, void* d_ws, size_t ws_size,
                              hipStream_t stream) {
  const float* x   = (const float*)d_in[0];
  const float* wgt = (const float*)d_in[1];
  float* out       = (float*)d_out;
  zero_upper<<<dim3(1024), dim3(256), 0, stream>>>(out);
  dwconv_tiles<<<dim3(NBLK), dim3(256), 0, stream>>>(x, wgt, out);
}